// Round 14
// baseline (38.639 us; speedup 1.0000x reference)
//
#include <hip/hip_runtime.h>
#include <stdint.h>

#define NDIM 1024
#define BATCH 16

typedef float fvec2 __attribute__((ext_vector_type(2)));

__device__ __forceinline__ float h2f(uint32_t bits16) {
    _Float16 h = __builtin_bit_cast(_Float16, (uint16_t)bits16);
    return (float)h;
}

// Fused spatially-varying 3x3 filter — R14: maximum-simplicity register-direct.
// R9-R13 A/B matrix (staging/sync/depth/conflicts/stores) all pinned at
// 3.3-3.9 TB/s; fillBuffer does 6.8 TB/s at 8% occupancy with a trivial loop.
// So: no LDS, no inline asm, 2 px/lane (float2), K fp16-packed (9 regs),
// double-buffered 9-reg patches -> live ~55 regs, comfortably under the
// allocator's 64-VGPR target (R4 sank the prefetch at exactly-64 pressure).
// 8192 waves (2048 blocks; 2x R10) each keeping next batch's 6 small loads
// in flight under the current apply. K built once per pixel (BCHUNK=16).
// Wave = 2 rows x 32 lanes x 2px; block = 4 waves = 64x8 tile.
struct RPatch {
    fvec2 m0, m1, m2;   // (j0, j0+1) for rows iT-1, iT, iT+1
    float h0, h1, h2;   // merged block-edge halo (lanes c==0 / c==31 only)
};

__global__ __launch_bounds__(256) void smallsm_fused(
    const float* __restrict__ image,
    const float* __restrict__ x,
    const float* __restrict__ w,
    const float* __restrict__ bias,
    float* __restrict__ out)
{
    const int N = NDIM;
    const size_t NN = (size_t)N * N;
    const int tid  = threadIdx.x;
    const int wid  = tid >> 6;             // wave 0..3
    const int lane = tid & 63;
    const int c    = lane & 31;            // 32 lanes in j (x2 px = 64 cols)
    const int g    = lane >> 5;            // row group 0..1 within wave
    const int jB   = blockIdx.x * 64;
    const int jT   = jB + c * 2;
    const int iT   = blockIdx.y * 8 + wid * 2 + g;

    const bool is_l = (c == 0);
    const bool is_r = (c == 31);
    const bool hp   = (is_l && jB > 0) || (is_r && jB + 64 < N);
    const int  hoff = is_r ? (jB + 64) : (jB - 1);

    // Issue loads for one 3-row, 2-wide patch (+ merged edge scalar).
    auto issue_patch = [&](const float* __restrict__ base, RPatch& p) {
#pragma unroll
        for (int r = 0; r < 3; ++r) {
            const int row = iT - 1 + r;
            const bool rv = (row >= 0) && (row < N);
            const float* rp = base + (size_t)row * N;
            fvec2 mv = {0.f, 0.f};
            if (rv) mv = *reinterpret_cast<const fvec2*>(rp + jT);
            float hv = 0.f;
            if (rv && hp) hv = rp[hoff];
            if (r == 0) { p.m0 = mv; p.h0 = hv; }
            if (r == 1) { p.m1 = mv; p.h1 = hv; }
            if (r == 2) { p.m2 = mv; p.h2 = hv; }
        }
    };

    // Raw patch -> 3x4 window (cols jT-1 .. jT+2) via neighbor-lane shuffles.
    auto finish_patch = [&](const RPatch& p, float (&v)[3][4]) {
#pragma unroll
        for (int r = 0; r < 3; ++r) {
            const fvec2 m  = (r == 0) ? p.m0 : (r == 1) ? p.m1 : p.m2;
            const float hv = (r == 0) ? p.h0 : (r == 1) ? p.h1 : p.h2;
            float left  = __shfl_up(m.y, 1);    // lane c-1's px j0+1
            float right = __shfl_down(m.x, 1);  // lane c+1's px j0
            if (is_l) left  = hv;
            if (is_r) right = hv;
            v[r][0] = left; v[r][1] = m.x; v[r][2] = m.y; v[r][3] = right;
        }
    };

    // ---- prologue: image patch + batch 0 patch in flight ----
    RPatch pim, PA, PB;
    issue_patch(image, pim);
    issue_patch(x, PA);
    __builtin_amdgcn_sched_barrier(0);

    // ---- build K (fp32 math), pack fp16x2 per tap -> Kp[9] ----
    uint32_t Kp[9];
    {
        float im[3][4];
        finish_patch(pim, im);
#pragma unroll
        for (int p = 0; p < 9; ++p) {
            const float bv = bias[p];
            float a0 = bv, a1 = bv;
#pragma unroll
            for (int m = 0; m < 3; ++m) {
#pragma unroll
                for (int n = 0; n < 3; ++n) {
                    const float wv = w[p * 9 + m * 3 + n];
                    a0 += wv * im[m][n];
                    a1 += wv * im[m][n + 1];
                }
            }
            const uint16_t q0 = __builtin_bit_cast(uint16_t, (_Float16)a0);
            const uint16_t q1 = __builtin_bit_cast(uint16_t, (_Float16)a1);
            Kp[p] = (uint32_t)q0 | ((uint32_t)q1 << 16);
        }
    }

    // ---- apply batch t from patch, store float2 ----
    auto apply = [&](int t, const RPatch& p) {
        float v[3][4];
        finish_patch(p, v);
        float a0 = 0.f, a1 = 0.f;
#pragma unroll
        for (int r = 0; r < 3; ++r) {
#pragma unroll
            for (int l = 0; l < 3; ++l) {
                const uint32_t u = Kp[3 * r + l];
                a0 += h2f(u & 0xffffu) * v[r][l];
                a1 += h2f(u >> 16)     * v[r][l + 1];
            }
        }
        fvec2 res; res.x = a0; res.y = a1;
        *reinterpret_cast<fvec2*>(out + (size_t)t * NN + (size_t)iT * N + jT) = res;
    };

    // ---- 16-batch double-buffered loop: prefetch t+1 while applying t.
    //      No asm waits: compiler inserts exact vmcnt for each buffer's use;
    //      sched_barrier(0) only stops the prefetch from sinking below apply.
#define STEP(T, CUR, NXT) do {                                   \
        if ((T) + 1 < BATCH) issue_patch(x + (size_t)((T)+1) * NN, NXT); \
        __builtin_amdgcn_sched_barrier(0);                       \
        apply((T), CUR);                                         \
    } while (0)

    STEP(0,  PA, PB); STEP(1,  PB, PA);
    STEP(2,  PA, PB); STEP(3,  PB, PA);
    STEP(4,  PA, PB); STEP(5,  PB, PA);
    STEP(6,  PA, PB); STEP(7,  PB, PA);
    STEP(8,  PA, PB); STEP(9,  PB, PA);
    STEP(10, PA, PB); STEP(11, PB, PA);
    STEP(12, PA, PB); STEP(13, PB, PA);
    STEP(14, PA, PB); STEP(15, PB, PA);
#undef STEP
}

extern "C" void kernel_launch(void* const* d_in, const int* in_sizes, int n_in,
                              void* d_out, int out_size, void* d_ws, size_t ws_size,
                              hipStream_t stream) {
    const float* image = (const float*)d_in[0];
    const float* x     = (const float*)d_in[1];
    const float* w     = (const float*)d_in[2];
    const float* bias  = (const float*)d_in[3];
    float* outp = (float*)d_out;

    dim3 grid(NDIM / 64, NDIM / 8, 1);   // 16 x 128 = 2048 blocks, 8192 waves
    dim3 block(256);
    hipLaunchKernelGGL(smallsm_fused, grid, block, 0, stream,
                       image, x, w, bias, outp);
}

// Round 15
// 37.110 us; speedup vs baseline: 1.0412x; 1.0412x over previous
//
#include <hip/hip_runtime.h>
#include <stdint.h>

#define NDIM 1024
#define BATCH 16

typedef float fvec4 __attribute__((ext_vector_type(4)));

__device__ __forceinline__ float h2f(uint32_t b) {
    _Float16 h = __builtin_bit_cast(_Float16, (uint16_t)b);
    return (float)h;
}

// R15: tile aspect flipped to full-wave-contiguous rows.
// Every prior round (R1-R14) used 64-wide tiles -> 256-288B per-instruction
// granules, and ALL pinned at 3.3-3.9 TB/s wall regardless of staging/sync/
// depth/occupancy. Ceiling-achieving kernels on this chip (m13 copy 6.3,
// fillBuffer 6.8) issue >=1KB contiguous per wave instruction. Here:
// wave = 1 output row x 256 px (4 px/lane) -> every x row load and out store
// is 64 lanes x 16B = 1KB contiguous. Block = 4 waves = 4 rows x 256 cols.
// Register double-buffered batch pipeline (R14 structure), shuffle halos,
// K built once per px, fp16x2-packed (18 VGPRs). Live ~59 regs < 64 target.
struct RPatch {
    fvec4 m0, m1, m2;   // cols jT..jT+3 for rows iT-1, iT, iT+1
    float h0, h1, h2;   // merged wave-edge halo (lane 0: jW-1; lane 63: jW+256)
};

__global__ __launch_bounds__(256) void smallsm_fused(
    const float* __restrict__ image,
    const float* __restrict__ x,
    const float* __restrict__ w,
    const float* __restrict__ bias,
    float* __restrict__ out)
{
    const int N = NDIM;
    const size_t NN = (size_t)N * N;
    const int tid  = threadIdx.x;
    const int wid  = tid >> 6;             // wave 0..3 -> row within block tile
    const int lane = tid & 63;
    const int jW   = blockIdx.x * 256;     // wave col base (256-px span)
    const int jT   = jW + lane * 4;        // lane col base (4 px)
    const int iT   = blockIdx.y * 4 + wid; // output row

    const bool is_l = (lane == 0);
    const bool is_r = (lane == 63);
    const bool hp   = (is_l && jW > 0) || (is_r && jW + 256 < N);
    const int  hoff = is_r ? (jW + 256) : (jW - 1);

    // Issue loads for one 3-row patch: 3 x 1KB contiguous + 1 merged scalar.
    auto issue_patch = [&](const float* __restrict__ base, RPatch& p) {
#pragma unroll
        for (int r = 0; r < 3; ++r) {
            const int row = iT - 1 + r;
            const bool rv = (row >= 0) && (row < N);
            const float* rp = base + (size_t)row * N;
            fvec4 mv = {0.f, 0.f, 0.f, 0.f};
            if (rv) mv = *reinterpret_cast<const fvec4*>(rp + jT);
            float hv = 0.f;
            if (rv && hp) hv = rp[hoff];   // lanes {0,63} only
            if (r == 0) { p.m0 = mv; p.h0 = hv; }
            if (r == 1) { p.m1 = mv; p.h1 = hv; }
            if (r == 2) { p.m2 = mv; p.h2 = hv; }
        }
    };

    // Raw patch -> 3x6 window (cols jT-1 .. jT+4) via neighbor-lane shuffles.
    auto finish_patch = [&](const RPatch& p, float (&v)[3][6]) {
#pragma unroll
        for (int r = 0; r < 3; ++r) {
            const fvec4 m  = (r == 0) ? p.m0 : (r == 1) ? p.m1 : p.m2;
            const float hv = (r == 0) ? p.h0 : (r == 1) ? p.h1 : p.h2;
            float left  = __shfl_up(m.w, 1);    // lane-1's col+3 = my col-1
            float right = __shfl_down(m.x, 1);  // lane+1's col  = my col+4
            if (is_l) left  = hv;
            if (is_r) right = hv;
            v[r][0] = left; v[r][1] = m.x; v[r][2] = m.y;
            v[r][3] = m.z;  v[r][4] = m.w; v[r][5] = right;
        }
    };

    // ---- prologue: image patch + batch 0 patch in flight ----
    RPatch pim, PA, PB;
    issue_patch(image, pim);
    issue_patch(x, PA);
    __builtin_amdgcn_sched_barrier(0);

    // ---- build K (fp32 math), pack fp16x2 -> Kp[18] (4 px x 9 taps) ----
    uint32_t Kp[18];
    {
        float im[3][6];
        finish_patch(pim, im);
#pragma unroll
        for (int p = 0; p < 9; ++p) {
            const float bv = bias[p];
            float a0 = bv, a1 = bv, a2 = bv, a3 = bv;
#pragma unroll
            for (int m = 0; m < 3; ++m) {
#pragma unroll
                for (int n = 0; n < 3; ++n) {
                    const float wv = w[p * 9 + m * 3 + n];
                    a0 += wv * im[m][n];
                    a1 += wv * im[m][n + 1];
                    a2 += wv * im[m][n + 2];
                    a3 += wv * im[m][n + 3];
                }
            }
            const uint16_t q0 = __builtin_bit_cast(uint16_t, (_Float16)a0);
            const uint16_t q1 = __builtin_bit_cast(uint16_t, (_Float16)a1);
            const uint16_t q2 = __builtin_bit_cast(uint16_t, (_Float16)a2);
            const uint16_t q3 = __builtin_bit_cast(uint16_t, (_Float16)a3);
            Kp[2 * p]     = (uint32_t)q0 | ((uint32_t)q1 << 16);
            Kp[2 * p + 1] = (uint32_t)q2 | ((uint32_t)q3 << 16);
        }
    }

    // ---- apply batch t from patch, store 1KB-contiguous fvec4 ----
    auto apply = [&](int t, const RPatch& p) {
        float v[3][6];
        finish_patch(p, v);
        float a0 = 0.f, a1 = 0.f, a2 = 0.f, a3 = 0.f;
#pragma unroll
        for (int r = 0; r < 3; ++r) {
#pragma unroll
            for (int l = 0; l < 3; ++l) {
                const int pp = 3 * r + l;
                const uint32_t u0 = Kp[2 * pp], u1 = Kp[2 * pp + 1];
                a0 += h2f(u0 & 0xffffu) * v[r][l];
                a1 += h2f(u0 >> 16)     * v[r][l + 1];
                a2 += h2f(u1 & 0xffffu) * v[r][l + 2];
                a3 += h2f(u1 >> 16)     * v[r][l + 3];
            }
        }
        fvec4 res; res.x = a0; res.y = a1; res.z = a2; res.w = a3;
        *reinterpret_cast<fvec4*>(out + (size_t)t * NN + (size_t)iT * N + jT) = res;
    };

    // ---- 16-batch double-buffered loop: prefetch t+1 while applying t ----
#define STEP(T, CUR, NXT) do {                                           \
        if ((T) + 1 < BATCH) issue_patch(x + (size_t)((T) + 1) * NN, NXT); \
        __builtin_amdgcn_sched_barrier(0);                               \
        apply((T), CUR);                                                 \
    } while (0)

    STEP(0,  PA, PB); STEP(1,  PB, PA);
    STEP(2,  PA, PB); STEP(3,  PB, PA);
    STEP(4,  PA, PB); STEP(5,  PB, PA);
    STEP(6,  PA, PB); STEP(7,  PB, PA);
    STEP(8,  PA, PB); STEP(9,  PB, PA);
    STEP(10, PA, PB); STEP(11, PB, PA);
    STEP(12, PA, PB); STEP(13, PB, PA);
    STEP(14, PA, PB); STEP(15, PB, PA);
#undef STEP
}

extern "C" void kernel_launch(void* const* d_in, const int* in_sizes, int n_in,
                              void* d_out, int out_size, void* d_ws, size_t ws_size,
                              hipStream_t stream) {
    const float* image = (const float*)d_in[0];
    const float* x     = (const float*)d_in[1];
    const float* w     = (const float*)d_in[2];
    const float* bias  = (const float*)d_in[3];
    float* outp = (float*)d_out;

    dim3 grid(NDIM / 256, NDIM / 4, 1);   // 4 x 256 = 1024 blocks, 4096 waves
    dim3 block(256);
    hipLaunchKernelGGL(smallsm_fused, grid, block, 0, stream,
                       image, x, w, bias, outp);
}